// Round 5
// baseline (427.922 us; speedup 1.0000x reference)
//
#include <hip/hip_runtime.h>

#define NDET 5000
#define NCLS 80
#define DSTR 84      // 4 box coords + 80 class scores
#define TOPK 1000
#define CROP 14
#define NPIX (CROP * CROP)   // 196
#define C    256

#define RCH 256      // rank chunk (i-chunk == j-chunk == block size)
#define NCH 20       // ceil(5000 / 256)

typedef float v4f __attribute__((ext_vector_type(4)));

// ---------------- Phase 1: fused scores + rank ------------------------------
// R5: one kernel instead of two (scores_kernel + rank_kernel). Each block owns
// i-range [256b, 256b+256). It loops over all 20 j-chunks, recomputing that
// chunk's 256 scores into LDS (det is 1.7 MB; redundant compute is ~free),
// captures its own score from the c==0 chunk, and accumulates
//   rank(i) = #{j : s_j > s_i} + #{j < i : s_j == s_i}   (jax.lax.top_k order)
// Rank is written ONCE per i -> no atomics, no zero-init kernel, one fewer
// graph node. Score max-tree is bitwise-identical to the old scores_kernel.
__global__ __launch_bounds__(RCH) void rank_fused_kernel(const float* __restrict__ det,
                                                         int* __restrict__ rank) {
    __shared__ float s[RCH];
    int b = blockIdx.x;           // 0..19
    int t = threadIdx.x;
    int i = b * RCH + t;          // my detection index (may be >= NDET)
    float my = -__builtin_inff();
    int r = 0;
    for (int c = 0; c < NCH; ++c) {
        int jc = b + c; if (jc >= NCH) jc -= NCH;   // start at own chunk
        int row = jc * RCH + t;
        float sc = -__builtin_inff();
        if (row < NDET) {
            const v4f* cls = (const v4f*)(det + row * DSTR + 4);  // 16B-aligned
            v4f m4 = cls[0];
            #pragma unroll
            for (int cc = 1; cc < NCLS / 4; ++cc) {
                v4f v = cls[cc];
                m4.x = fmaxf(m4.x, v.x); m4.y = fmaxf(m4.y, v.y);
                m4.z = fmaxf(m4.z, v.z); m4.w = fmaxf(m4.w, v.w);
            }
            sc = fmaxf(fmaxf(m4.x, m4.y), fmaxf(m4.z, m4.w));
        }
        s[t] = sc;
        __syncthreads();
        if (c == 0) my = s[t];    // own chunk staged first
        int jbase = jc * RCH;
        #pragma unroll 8
        for (int u = 0; u < RCH; ++u) {
            float v = s[u];
            int j = jbase + u;
            r += (v > my) | ((v == my) & (j < i));
        }
        __syncthreads();
    }
    if (i < NDET) rank[i] = r;
}

// ---------------- Phase 2: scatter + stable level sort + per-slot params ----
// Scatter rank->topk_idx in LDS; packed-key prefix scan (5 levels, counts
// < 4096) for the stable sort; level computed INLINE from det (same float
// formula as reference; lvl_all array dropped); then per-slot params
// {x1n, y1n, x2n-x1n, y2n-y1n} with the SAME float ops as reference.
__global__ __launch_bounds__(1024) void order_kernel(const float* __restrict__ det,
                                                     const int* __restrict__ rank,
                                                     v4f* __restrict__ slot_params,
                                                     int* __restrict__ slot_level) {
    __shared__ int topk_idx_s[TOPK];
    __shared__ unsigned long long wave_tot[16];
    int r = threadIdx.x;
    for (int i = r; i < NDET; i += 1024) {
        int rk = rank[i];
        if (rk < TOPK) topk_idx_s[rk] = i;
    }
    __syncthreads();

    int di = 0, L = 0;
    v4f box = {0.f, 0.f, 0.f, 0.f};
    unsigned long long key = 0;
    if (r < TOPK) {
        di = topk_idx_s[r];
        box = *(const v4f*)(det + di * DSTR);     // row base is 16B-aligned
        // level = clip(floor(1 + log2(sqrt(w*h)/224 + 1e-7)), 0, 4)
        float w = box.z - box.x;
        float h = box.w - box.y;
        float sz = sqrtf(w * h);
        float lf = floorf(1.0f + log2f(sz / 224.0f + 1e-7f));
        lf = fminf(fmaxf(lf, 0.0f), 4.0f);
        L = (int)lf;
        key = 1ULL << (12 * L);
    }
    unsigned long long incl = key;
    #pragma unroll
    for (int d = 1; d < 64; d <<= 1) {
        unsigned long long up = __shfl_up(incl, d, 64);
        if ((r & 63) >= d) incl += up;
    }
    int wave = r >> 6;
    if ((r & 63) == 63) wave_tot[wave] = incl;
    __syncthreads();
    unsigned long long waveoff = 0, total = 0;
    for (int w = 0; w < 16; ++w) {
        unsigned long long t = wave_tot[w];
        if (w < wave) waveoff += t;
        total += t;
    }
    if (r < TOPK) {
        unsigned long long excl = waveoff + incl - key;
        int base = 0;
        for (int l = 0; l < L; ++l) base += (int)((total >> (12 * l)) & 0xFFF);
        int within = (int)((excl >> (12 * L)) & 0xFFF);
        int pos = base + within;
        int H = 256 >> L;
        float hf = (float)(H - 1);
        float x1n = box.x / hf, y1n = box.y / hf;
        float x2n = box.z / hf, y2n = box.w / hf;   // W == H per level
        v4f prm = {x1n, y1n, x2n - x1n, y2n - y1n};
        slot_params[pos] = prm;
        slot_level[pos] = L;
    }
}

// ---------------- Phase 3: crop_and_resize main kernel ----------------------
// EXACT R0 structure (best measured: 281.9 us): 49 blocks/box, 1 wave = 1
// pixel, lane = 4 contiguous channels, normal stores, no swizzle. Per-wave
// preamble is one broadcast 16B param load + 4B level load.
__global__ __launch_bounds__(256) void crop_kernel(
    const float* __restrict__ p0, const float* __restrict__ p1,
    const float* __restrict__ p2, const float* __restrict__ p3,
    const float* __restrict__ p4,
    const v4f* __restrict__ slot_params, const int* __restrict__ slot_level,
    float* __restrict__ out)
{
    int wave = threadIdx.x >> 6;
    int lane = threadIdx.x & 63;
    int slot = blockIdx.x / 49;
    int p    = (blockIdx.x % 49) * 4 + wave;   // pixel index 0..195
    int py = p / CROP, px = p - py * CROP;

    int L = slot_level[slot];
    const float* feat;
    switch (L) {
        case 0:  feat = p0; break;
        case 1:  feat = p1; break;
        case 2:  feat = p2; break;
        case 3:  feat = p3; break;
        default: feat = p4; break;
    }
    int H = 256 >> L;
    float hf = (float)(H - 1);

    v4f prm = slot_params[slot];
    float ty = (float)py / 13.0f;
    float tx = (float)px / 13.0f;
    float ys = (prm.y + prm.w * ty) * hf;
    float xs = (prm.x + prm.z * tx) * hf;

    v4f* outp = (v4f*)(out + (size_t)(slot * NPIX + p) * C) + lane;

    bool valid = (ys >= 0.0f) & (ys <= hf) & (xs >= 0.0f) & (xs <= hf);
    if (!valid) {
        v4f z = {0.0f, 0.0f, 0.0f, 0.0f};
        *outp = z;
        return;
    }

    float y0f = floorf(ys), x0f = floorf(xs);
    float ly = ys - y0f,    lx = xs - x0f;
    int y0i = (int)fminf(fmaxf(y0f,        0.0f), hf);
    int y1i = (int)fminf(fmaxf(y0f + 1.0f, 0.0f), hf);
    int x0i = (int)fminf(fmaxf(x0f,        0.0f), hf);
    int x1i = (int)fminf(fmaxf(x0f + 1.0f, 0.0f), hf);

    v4f f00 = ((const v4f*)(feat + (size_t)(y0i * H + x0i) * C))[lane];
    v4f f01 = ((const v4f*)(feat + (size_t)(y0i * H + x1i) * C))[lane];
    v4f f10 = ((const v4f*)(feat + (size_t)(y1i * H + x0i) * C))[lane];
    v4f f11 = ((const v4f*)(feat + (size_t)(y1i * H + x1i) * C))[lane];

    v4f top = f00 + (f01 - f00) * lx;
    v4f bot = f10 + (f11 - f10) * lx;
    v4f o   = top + (bot - top) * ly;
    *outp = o;
}

extern "C" void kernel_launch(void* const* d_in, const int* in_sizes, int n_in,
                              void* d_out, int out_size, void* d_ws, size_t ws_size,
                              hipStream_t stream) {
    const float* det = (const float*)d_in[0];
    const float* p0  = (const float*)d_in[1];
    const float* p1  = (const float*)d_in[2];
    const float* p2  = (const float*)d_in[3];
    const float* p3  = (const float*)d_in[4];
    const float* p4  = (const float*)d_in[5];
    float* out = (float*)d_out;

    char* ws = (char*)d_ws;
    int*   rank        = (int*)(ws + 0);          // 5000 ints
    v4f*   slot_params = (v4f*)(ws + 20032);      // 1000 float4 (16B-aligned)
    int*   slot_lvl    = (int*)(ws + 36032);      // 1000 ints

    rank_fused_kernel<<<NCH, RCH, 0, stream>>>(det, rank);
    order_kernel<<<1, 1024, 0, stream>>>(det, rank, slot_params, slot_lvl);
    crop_kernel<<<TOPK * 49, 256, 0, stream>>>(p0, p1, p2, p3, p4,
                                               slot_params, slot_lvl, out);
}

// Round 6
// 306.190 us; speedup vs baseline: 1.3976x; 1.3976x over previous
//
#include <hip/hip_runtime.h>

#define NDET 5000
#define NCLS 80
#define DSTR 84      // 4 box coords + 80 class scores
#define TOPK 1000
#define CROP 14
#define NPIX (CROP * CROP)   // 196
#define C    256

#define JCHUNK 250
#define ICHUNK 256

// crop_v6 geometry: 2048 blocks x 4 waves = 8192 waves; each wave owns
// PPW contiguous pixels (1 KB store each). 8192*24 = 196608 >= 196000.
#define CROP_BLOCKS 2048
#define PPW 24

typedef float v4f __attribute__((ext_vector_type(4)));

// ---------------- Phase 1a: scores (vectorized) -----------------------------
// Proven R0 kernel (minus the lvl_all write; order computes level inline).
__global__ void scores_kernel(const float* __restrict__ det, float* __restrict__ scores,
                              int* __restrict__ rank) {
    int i = blockIdx.x * blockDim.x + threadIdx.x;
    if (i >= NDET) return;
    const float* row = det + i * DSTR;
    // class scores at row+4: 80 floats, 16B-aligned (336*i + 16)
    const v4f* cls = (const v4f*)(row + 4);
    v4f m4 = cls[0];
    #pragma unroll
    for (int c = 1; c < NCLS / 4; ++c) {
        v4f v = cls[c];
        m4.x = fmaxf(m4.x, v.x); m4.y = fmaxf(m4.y, v.y);
        m4.z = fmaxf(m4.z, v.z); m4.w = fmaxf(m4.w, v.w);
    }
    scores[i] = fmaxf(fmaxf(m4.x, m4.y), fmaxf(m4.z, m4.w));
    rank[i] = 0;
}

// ---------------- Phase 1b: distributed rank counting (proven R0) -----------
// rank(i) = #{j : s_j > s_i} + #{j < i : s_j == s_i}   (jax.lax.top_k order)
__global__ __launch_bounds__(ICHUNK) void rank_kernel(const float* __restrict__ scores,
                                                      int* __restrict__ rank) {
    __shared__ float s[JCHUNK];
    int jbase = blockIdx.y * JCHUNK;
    for (int t = threadIdx.x; t < JCHUNK; t += blockDim.x) s[t] = scores[jbase + t];
    __syncthreads();
    int i = blockIdx.x * ICHUNK + threadIdx.x;
    if (i >= NDET) return;
    float my = scores[i];
    int r = 0;
    #pragma unroll 5
    for (int t = 0; t < JCHUNK; ++t) {
        float v = s[t];
        int j = jbase + t;
        r += (v > my) | ((v == my) & (j < i));
    }
    atomicAdd(&rank[i], r);
}

// ---------------- Phase 2: scatter + stable level sort + per-slot params ----
// R5 version (passed): level computed inline from det; packed-key prefix scan
// (5 levels, counts < 4096) for the stable sort; per-slot params
// {x1n, y1n, x2n-x1n, y2n-y1n} with the SAME float ops as reference.
__global__ __launch_bounds__(1024) void order_kernel(const float* __restrict__ det,
                                                     const int* __restrict__ rank,
                                                     v4f* __restrict__ slot_params,
                                                     int* __restrict__ slot_level) {
    __shared__ int topk_idx_s[TOPK];
    __shared__ unsigned long long wave_tot[16];
    int r = threadIdx.x;
    for (int i = r; i < NDET; i += 1024) {
        int rk = rank[i];
        if (rk < TOPK) topk_idx_s[rk] = i;
    }
    __syncthreads();

    int di = 0, L = 0;
    v4f box = {0.f, 0.f, 0.f, 0.f};
    unsigned long long key = 0;
    if (r < TOPK) {
        di = topk_idx_s[r];
        box = *(const v4f*)(det + di * DSTR);     // row base is 16B-aligned
        // level = clip(floor(1 + log2(sqrt(w*h)/224 + 1e-7)), 0, 4)
        float w = box.z - box.x;
        float h = box.w - box.y;
        float sz = sqrtf(w * h);
        float lf = floorf(1.0f + log2f(sz / 224.0f + 1e-7f));
        lf = fminf(fmaxf(lf, 0.0f), 4.0f);
        L = (int)lf;
        key = 1ULL << (12 * L);
    }
    unsigned long long incl = key;
    #pragma unroll
    for (int d = 1; d < 64; d <<= 1) {
        unsigned long long up = __shfl_up(incl, d, 64);
        if ((r & 63) >= d) incl += up;
    }
    int wave = r >> 6;
    if ((r & 63) == 63) wave_tot[wave] = incl;
    __syncthreads();
    unsigned long long waveoff = 0, total = 0;
    for (int w = 0; w < 16; ++w) {
        unsigned long long t = wave_tot[w];
        if (w < wave) waveoff += t;
        total += t;
    }
    if (r < TOPK) {
        unsigned long long excl = waveoff + incl - key;
        int base = 0;
        for (int l = 0; l < L; ++l) base += (int)((total >> (12 * l)) & 0xFFF);
        int within = (int)((excl >> (12 * L)) & 0xFFF);
        int pos = base + within;
        int H = 256 >> L;
        float hf = (float)(H - 1);
        float x1n = box.x / hf, y1n = box.y / hf;
        float x2n = box.z / hf, y2n = box.w / hf;   // W == H per level
        v4f prm = {x1n, y1n, x2n - x1n, y2n - y1n};
        slot_params[pos] = prm;
        slot_level[pos] = L;
    }
}

// ---------------- Phase 3: crop_and_resize, grid-stride structure -----------
// R6 restructure of the ~100us R0 crop (49000 one-store blocks -> dispatch-
// rate bound ~2 TB/s). Fill-kernel recipe applied to crop itself:
// 2048 blocks (8/CU), each wave owns PPW=24 CONTIGUOUS pixels. Balanced
// (zero vs bilinear pixels average out), per-wave preamble amortized over
// 24 KB of stores, write stream is a contiguous partition of the output.
// Slot params/level reload per pixel is a wave-uniform scalar load from a
// 20 KB L2-resident table.
__global__ __launch_bounds__(256) void crop_kernel(
    const float* __restrict__ p0, const float* __restrict__ p1,
    const float* __restrict__ p2, const float* __restrict__ p3,
    const float* __restrict__ p4,
    const v4f* __restrict__ slot_params, const int* __restrict__ slot_level,
    float* __restrict__ out)
{
    int wave = threadIdx.x >> 6;
    int lane = threadIdx.x & 63;
    int gw   = blockIdx.x * 4 + wave;       // global wave id 0..8191
    int u    = gw * PPW;                    // first pixel-unit (slot*196 + p)
    int uend = u + PPW;
    if (u >= TOPK * NPIX) return;
    if (uend > TOPK * NPIX) uend = TOPK * NPIX;

    int cur_slot = -1;
    const float* feat = p0;
    int H = 256;
    float hf = 255.0f;
    v4f prm = {0.f, 0.f, 0.f, 0.f};

    v4f z = {0.0f, 0.0f, 0.0f, 0.0f};

    for (; u < uend; ++u) {
        int slot = u / NPIX;                // compile-time magic-mul
        int p    = u - slot * NPIX;
        if (slot != cur_slot) {
            cur_slot = slot;
            int L = slot_level[slot];       // wave-uniform scalar load
            switch (L) {
                case 0:  feat = p0; break;
                case 1:  feat = p1; break;
                case 2:  feat = p2; break;
                case 3:  feat = p3; break;
                default: feat = p4; break;
            }
            H = 256 >> L;
            hf = (float)(H - 1);
            prm = slot_params[slot];
        }
        int py = p / CROP, px = p - py * CROP;
        float ty = (float)py / 13.0f;
        float tx = (float)px / 13.0f;
        float ys = (prm.y + prm.w * ty) * hf;
        float xs = (prm.x + prm.z * tx) * hf;

        v4f* outp = (v4f*)(out + (size_t)u * C) + lane;

        bool valid = (ys >= 0.0f) & (ys <= hf) & (xs >= 0.0f) & (xs <= hf);
        if (!valid) {
            *outp = z;
            continue;
        }

        float y0f = floorf(ys), x0f = floorf(xs);
        float ly = ys - y0f,    lx = xs - x0f;
        int y0i = (int)fminf(fmaxf(y0f,        0.0f), hf);
        int y1i = (int)fminf(fmaxf(y0f + 1.0f, 0.0f), hf);
        int x0i = (int)fminf(fmaxf(x0f,        0.0f), hf);
        int x1i = (int)fminf(fmaxf(x0f + 1.0f, 0.0f), hf);

        v4f f00 = ((const v4f*)(feat + (size_t)(y0i * H + x0i) * C))[lane];
        v4f f01 = ((const v4f*)(feat + (size_t)(y0i * H + x1i) * C))[lane];
        v4f f10 = ((const v4f*)(feat + (size_t)(y1i * H + x0i) * C))[lane];
        v4f f11 = ((const v4f*)(feat + (size_t)(y1i * H + x1i) * C))[lane];

        v4f top = f00 + (f01 - f00) * lx;
        v4f bot = f10 + (f11 - f10) * lx;
        v4f o   = top + (bot - top) * ly;
        *outp = o;
    }
}

extern "C" void kernel_launch(void* const* d_in, const int* in_sizes, int n_in,
                              void* d_out, int out_size, void* d_ws, size_t ws_size,
                              hipStream_t stream) {
    const float* det = (const float*)d_in[0];
    const float* p0  = (const float*)d_in[1];
    const float* p1  = (const float*)d_in[2];
    const float* p2  = (const float*)d_in[3];
    const float* p3  = (const float*)d_in[4];
    const float* p4  = (const float*)d_in[5];
    float* out = (float*)d_out;

    char* ws = (char*)d_ws;
    float* scores      = (float*)(ws + 0);        // 5000 floats
    int*   rank        = (int*)(ws + 20000);      // 5000 ints
    v4f*   slot_params = (v4f*)(ws + 40000);      // 1000 float4 (16B-aligned)
    int*   slot_lvl    = (int*)(ws + 56000);      // 1000 ints

    scores_kernel<<<(NDET + 255) / 256, 256, 0, stream>>>(det, scores, rank);
    dim3 rg((NDET + ICHUNK - 1) / ICHUNK, NDET / JCHUNK);
    rank_kernel<<<rg, ICHUNK, 0, stream>>>(scores, rank);
    order_kernel<<<1, 1024, 0, stream>>>(det, rank, slot_params, slot_lvl);
    crop_kernel<<<CROP_BLOCKS, 256, 0, stream>>>(p0, p1, p2, p3, p4,
                                                 slot_params, slot_lvl, out);
}

// Round 7
// 282.741 us; speedup vs baseline: 1.5135x; 1.0829x over previous
//
#include <hip/hip_runtime.h>

#define NDET 5000
#define NCLS 80
#define DSTR 84      // 4 box coords + 80 class scores
#define TOPK 1000
#define CROP 14
#define NPIX (CROP * CROP)   // 196
#define C    256

#define RCHK 250     // rank chunk size (5000 = 20 x 250)
#define NCHK 20

typedef float v4f __attribute__((ext_vector_type(4)));

// Score maxtree — the ONE definition used for both the i-role and j-role so
// results are bitwise identical everywhere (required for the rank tie-break).
__device__ __forceinline__ float det_score(const float* __restrict__ det, int i) {
    const v4f* cls = (const v4f*)(det + i * DSTR + 4);   // 336*i+16: 16B-aligned
    v4f m4 = cls[0];
    #pragma unroll
    for (int c = 1; c < NCLS / 4; ++c) {
        v4f v = cls[c];
        m4.x = fmaxf(m4.x, v.x); m4.y = fmaxf(m4.y, v.y);
        m4.z = fmaxf(m4.z, v.z); m4.w = fmaxf(m4.w, v.w);
    }
    return fmaxf(fmaxf(m4.x, m4.y), fmaxf(m4.z, m4.w));
}

// ---------------- Phase 1: fused scores + rank partials ---------------------
// R7: one node instead of two, at FULL parallelism (R5's 20-block fusion was
// the anti-pattern: 1 wave/SIMD, 164 us). dim3(20,20) = 400 blocks; block
// (bi,bj) stages j-chunk scores in LDS (recomputed from the L2-resident
// 1.7 MB det — redundant compute is cheap), computes its own i-scores, and
// writes the chunk-partial rank
//   r_part(i, bj) = #{j in chunk bj : s_j > s_i} + #{j in chunk bj, j < i : s_j == s_i}
// to rank_part[bj][i] (coalesced u16). No atomics -> no zero-init pass.
// order sums the 20 partials per i (jax.lax.top_k order preserved exactly).
__global__ __launch_bounds__(256) void rank_fused(const float* __restrict__ det,
                                                  unsigned short* __restrict__ rank_part) {
    __shared__ float s[RCHK];
    int bi = blockIdx.x, bj = blockIdx.y;
    int t = threadIdx.x;
    if (t < RCHK) s[t] = det_score(det, bj * RCHK + t);
    __syncthreads();
    if (t >= RCHK) return;
    int i = bi * RCHK + t;
    float my = det_score(det, i);
    int jbase = bj * RCHK;
    int r = 0;
    #pragma unroll 5
    for (int u = 0; u < RCHK; ++u) {
        float v = s[u];
        int j = jbase + u;
        r += (v > my) | ((v == my) & (j < i));
    }
    rank_part[bj * NDET + i] = (unsigned short)r;
}

// ---------------- Phase 2: scatter + stable level sort + per-slot params ----
// R5-proven structure; scatter loop now sums the 20 rank partials per i
// (coalesced: consecutive threads read consecutive i within each bj-plane).
// Level computed inline from det with the reference's exact float formula;
// packed-key prefix scan (5 levels, counts < 4096) for the stable sort.
__global__ __launch_bounds__(1024) void order_kernel(const float* __restrict__ det,
                                                     const unsigned short* __restrict__ rank_part,
                                                     v4f* __restrict__ slot_params,
                                                     int* __restrict__ slot_level) {
    __shared__ int topk_idx_s[TOPK];
    __shared__ unsigned long long wave_tot[16];
    int r = threadIdx.x;
    for (int i = r; i < NDET; i += 1024) {
        int rk = 0;
        #pragma unroll
        for (int k = 0; k < NCHK; ++k) rk += rank_part[k * NDET + i];
        if (rk < TOPK) topk_idx_s[rk] = i;
    }
    __syncthreads();

    int di = 0, L = 0;
    v4f box = {0.f, 0.f, 0.f, 0.f};
    unsigned long long key = 0;
    if (r < TOPK) {
        di = topk_idx_s[r];
        box = *(const v4f*)(det + di * DSTR);     // row base is 16B-aligned
        // level = clip(floor(1 + log2(sqrt(w*h)/224 + 1e-7)), 0, 4)
        float w = box.z - box.x;
        float h = box.w - box.y;
        float sz = sqrtf(w * h);
        float lf = floorf(1.0f + log2f(sz / 224.0f + 1e-7f));
        lf = fminf(fmaxf(lf, 0.0f), 4.0f);
        L = (int)lf;
        key = 1ULL << (12 * L);
    }
    unsigned long long incl = key;
    #pragma unroll
    for (int d = 1; d < 64; d <<= 1) {
        unsigned long long up = __shfl_up(incl, d, 64);
        if ((r & 63) >= d) incl += up;
    }
    int wave = r >> 6;
    if ((r & 63) == 63) wave_tot[wave] = incl;
    __syncthreads();
    unsigned long long waveoff = 0, total = 0;
    for (int w = 0; w < 16; ++w) {
        unsigned long long t = wave_tot[w];
        if (w < wave) waveoff += t;
        total += t;
    }
    if (r < TOPK) {
        unsigned long long excl = waveoff + incl - key;
        int base = 0;
        for (int l = 0; l < L; ++l) base += (int)((total >> (12 * l)) & 0xFFF);
        int within = (int)((excl >> (12 * L)) & 0xFFF);
        int pos = base + within;
        int H = 256 >> L;
        float hf = (float)(H - 1);
        float x1n = box.x / hf, y1n = box.y / hf;
        float x2n = box.z / hf, y2n = box.w / hf;   // W == H per level
        v4f prm = {x1n, y1n, x2n - x1n, y2n - y1n};
        slot_params[pos] = prm;
        slot_level[pos] = L;
    }
}

// ---------------- Phase 3: crop_and_resize main kernel ----------------------
// EXACT R0 structure, byte-for-byte (proven best across R0-R6; ~10 us: the
// 200 MB output is L3-resident so stores retire at cache rate, and 49000
// one-store waves maximize TLP with zero serial latency chains — every
// "fatter" restructure lost to latency-bound straggler loops).
__global__ __launch_bounds__(256) void crop_kernel(
    const float* __restrict__ p0, const float* __restrict__ p1,
    const float* __restrict__ p2, const float* __restrict__ p3,
    const float* __restrict__ p4,
    const v4f* __restrict__ slot_params, const int* __restrict__ slot_level,
    float* __restrict__ out)
{
    int wave = threadIdx.x >> 6;
    int lane = threadIdx.x & 63;
    int slot = blockIdx.x / 49;
    int p    = (blockIdx.x % 49) * 4 + wave;   // pixel index 0..195
    int py = p / CROP, px = p - py * CROP;

    int L = slot_level[slot];
    const float* feat;
    switch (L) {
        case 0:  feat = p0; break;
        case 1:  feat = p1; break;
        case 2:  feat = p2; break;
        case 3:  feat = p3; break;
        default: feat = p4; break;
    }
    int H = 256 >> L;
    float hf = (float)(H - 1);

    v4f prm = slot_params[slot];
    float ty = (float)py / 13.0f;
    float tx = (float)px / 13.0f;
    float ys = (prm.y + prm.w * ty) * hf;
    float xs = (prm.x + prm.z * tx) * hf;

    v4f* outp = (v4f*)(out + (size_t)(slot * NPIX + p) * C) + lane;

    bool valid = (ys >= 0.0f) & (ys <= hf) & (xs >= 0.0f) & (xs <= hf);
    if (!valid) {
        v4f z = {0.0f, 0.0f, 0.0f, 0.0f};
        *outp = z;
        return;
    }

    float y0f = floorf(ys), x0f = floorf(xs);
    float ly = ys - y0f,    lx = xs - x0f;
    int y0i = (int)fminf(fmaxf(y0f,        0.0f), hf);
    int y1i = (int)fminf(fmaxf(y0f + 1.0f, 0.0f), hf);
    int x0i = (int)fminf(fmaxf(x0f,        0.0f), hf);
    int x1i = (int)fminf(fmaxf(x0f + 1.0f, 0.0f), hf);

    v4f f00 = ((const v4f*)(feat + (size_t)(y0i * H + x0i) * C))[lane];
    v4f f01 = ((const v4f*)(feat + (size_t)(y0i * H + x1i) * C))[lane];
    v4f f10 = ((const v4f*)(feat + (size_t)(y1i * H + x0i) * C))[lane];
    v4f f11 = ((const v4f*)(feat + (size_t)(y1i * H + x1i) * C))[lane];

    v4f top = f00 + (f01 - f00) * lx;
    v4f bot = f10 + (f11 - f10) * lx;
    v4f o   = top + (bot - top) * ly;
    *outp = o;
}

extern "C" void kernel_launch(void* const* d_in, const int* in_sizes, int n_in,
                              void* d_out, int out_size, void* d_ws, size_t ws_size,
                              hipStream_t stream) {
    const float* det = (const float*)d_in[0];
    const float* p0  = (const float*)d_in[1];
    const float* p1  = (const float*)d_in[2];
    const float* p2  = (const float*)d_in[3];
    const float* p3  = (const float*)d_in[4];
    const float* p4  = (const float*)d_in[5];
    float* out = (float*)d_out;

    char* ws = (char*)d_ws;
    unsigned short* rank_part = (unsigned short*)(ws + 0);  // 20x5000 u16 = 200000 B
    v4f* slot_params = (v4f*)(ws + 200000);                 // 1000 float4 (16B-aligned)
    int* slot_lvl    = (int*)(ws + 216000);                 // 1000 ints

    rank_fused<<<dim3(NCHK, NCHK), 256, 0, stream>>>(det, rank_part);
    order_kernel<<<1, 1024, 0, stream>>>(det, rank_part, slot_params, slot_lvl);
    crop_kernel<<<TOPK * 49, 256, 0, stream>>>(p0, p1, p2, p3, p4,
                                               slot_params, slot_lvl, out);
}